// Round 1
// baseline (1718.191 us; speedup 1.0000x reference)
//
#include <hip/hip_runtime.h>
#include <math.h>

#define EPS 1e-12f

// ---- workspace layout (floats) ----
// 0        : Wt_s  (32*256)   = 8192
// 8192     : Wp_s  (32*256)   = 8192
// 16384    : Wg_s  (128*256)  = 32768
// 49152    : Wo_s  (256*128)  = 32768
// 81920    : theta (16*32*4096)  = 2097152
// 2179072  : phi   (16*32*1024)  = 524288   layout [n][c][m]
// 2703360  : g_t   (16*1024*128) = 2097152  layout [n][m][cg]
// total 4800512 floats = 19.2 MB

#define WS_THETA 81920
#define WS_PHI   2179072
#define WS_GT    2703360

__device__ __forceinline__ float block_reduce_sum(float v, float* red) {
  int t = threadIdx.x;
  red[t] = v;
  __syncthreads();
  #pragma unroll
  for (int s = 128; s > 0; s >>= 1) {
    if (t < s) red[t] += red[t + s];
    __syncthreads();
  }
  float r = red[0];
  __syncthreads();
  return r;
}

// One block per weight: spectral-norm scale W -> W/sigma into ws.
__global__ __launch_bounds__(256) void sn_kernel(
    const float* __restrict__ Wt, const float* __restrict__ Wp,
    const float* __restrict__ Wg, const float* __restrict__ Wo,
    const float* __restrict__ ut, const float* __restrict__ up,
    const float* __restrict__ ug, const float* __restrict__ uo,
    float* __restrict__ ws) {
  __shared__ float red[256];
  __shared__ float ub[256];
  __shared__ float vb[256];
  const float* W; const float* u; float* Wout; int O, Ci;
  switch (blockIdx.x) {
    case 0:  W = Wt; u = ut; Wout = ws;         O = 32;  Ci = 256; break;
    case 1:  W = Wp; u = up; Wout = ws + 8192;  O = 32;  Ci = 256; break;
    case 2:  W = Wg; u = ug; Wout = ws + 16384; O = 128; Ci = 256; break;
    default: W = Wo; u = uo; Wout = ws + 49152; O = 256; Ci = 128; break;
  }
  int t = threadIdx.x;
  if (t < O) ub[t] = u[t];
  __syncthreads();
  // tvec = W^T u
  float tv = 0.f;
  if (t < Ci) {
    for (int o = 0; o < O; o++) tv += W[o * Ci + t] * ub[o];
  }
  float nt2 = block_reduce_sum((t < Ci) ? tv * tv : 0.f, red);
  float ntn = sqrtf(nt2);
  if (t < Ci) vb[t] = tv / (ntn + EPS);
  __syncthreads();
  // s = W v ; sigma = ||s||^2 / (||s|| + eps)
  float sv = 0.f;
  if (t < O) {
    for (int c = 0; c < Ci; c++) sv += W[t * Ci + c] * vb[c];
  }
  float ss = block_reduce_sum((t < O) ? sv * sv : 0.f, red);
  float ns = sqrtf(ss);
  float sigma = ss / (ns + EPS);
  float inv = 1.f / sigma;
  int total = O * Ci;
  for (int i = t; i < total; i += 256) Wout[i] = W[i] * inv;
}

// theta[n][o][l] = sum_c Wt_s[o][c] x[n][c][l], o in [0,32)
__global__ __launch_bounds__(256) void theta_kernel(const float* __restrict__ x,
                                                    const float* __restrict__ Wsc,
                                                    float* __restrict__ theta) {
  __shared__ float4 Wl[32 * 64];   // [o][c4]  32 KB
  int t = threadIdx.x;
  const float4* W4 = (const float4*)Wsc;
  #pragma unroll
  for (int k = 0; k < 8; k++) Wl[t + k * 256] = W4[t + k * 256];
  __syncthreads();
  int n = blockIdx.y;
  int l = blockIdx.x * 256 + t;
  const float* xp = x + ((size_t)n * 256) * 4096 + l;
  float acc[32];
  #pragma unroll
  for (int o = 0; o < 32; o++) acc[o] = 0.f;
  for (int c4 = 0; c4 < 64; c4++) {
    float x0 = xp[(size_t)(c4 * 4 + 0) * 4096];
    float x1 = xp[(size_t)(c4 * 4 + 1) * 4096];
    float x2 = xp[(size_t)(c4 * 4 + 2) * 4096];
    float x3 = xp[(size_t)(c4 * 4 + 3) * 4096];
    #pragma unroll
    for (int o = 0; o < 32; o++) {
      float4 w = Wl[o * 64 + c4];
      acc[o] += w.x * x0 + w.y * x1 + w.z * x2 + w.w * x3;
    }
  }
  float* tp = theta + ((size_t)n * 32) * 4096 + l;
  #pragma unroll
  for (int o = 0; o < 32; o++) tp[(size_t)o * 4096] = acc[o];
}

// Pooled projections: og 0..1 -> phi rows (Wp_s), og 2..9 -> g rows (Wg_s).
// Each thread: one pooled pixel m, 16 output channels, max over 4 sub-pixels.
__global__ __launch_bounds__(256) void pool_proj_kernel(const float* __restrict__ x,
                                                        const float* __restrict__ ws,
                                                        float* __restrict__ phi,
                                                        float* __restrict__ g_t) {
  __shared__ float4 Wl[16 * 64];   // 16 KB
  int t = threadIdx.x;
  int og = blockIdx.z;  // 0..9
  const float* Wsrc = (og < 2) ? (ws + 8192 + og * 16 * 256)
                               : (ws + 16384 + (og - 2) * 16 * 256);
  const float4* W4 = (const float4*)Wsrc;
  #pragma unroll
  for (int k = 0; k < 4; k++) Wl[t + k * 256] = W4[t + k * 256];
  __syncthreads();
  int n = blockIdx.y;
  int m = blockIdx.x * 256 + t;
  int hd = m >> 5, wd = m & 31;
  int hw0 = hd * 128 + wd * 2;     // (2hd)*64 + 2wd
  const float* xp = x + ((size_t)n * 256) * 4096;
  float best[16];
  #pragma unroll 1
  for (int sub = 0; sub < 4; sub++) {
    int off = hw0 + ((sub >> 1) * 64) + (sub & 1);
    float acc[16];
    #pragma unroll
    for (int o = 0; o < 16; o++) acc[o] = 0.f;
    for (int c4 = 0; c4 < 64; c4++) {
      float x0 = xp[(size_t)(c4 * 4 + 0) * 4096 + off];
      float x1 = xp[(size_t)(c4 * 4 + 1) * 4096 + off];
      float x2 = xp[(size_t)(c4 * 4 + 2) * 4096 + off];
      float x3 = xp[(size_t)(c4 * 4 + 3) * 4096 + off];
      #pragma unroll
      for (int o = 0; o < 16; o++) {
        float4 w = Wl[o * 64 + c4];
        acc[o] += w.x * x0 + w.y * x1 + w.z * x2 + w.w * x3;
      }
    }
    if (sub == 0) {
      #pragma unroll
      for (int o = 0; o < 16; o++) best[o] = acc[o];
    } else {
      #pragma unroll
      for (int o = 0; o < 16; o++) best[o] = fmaxf(best[o], acc[o]);
    }
  }
  if (og < 2) {
    float* pp = phi + ((size_t)n * 32 + og * 16) * 1024 + m;
    #pragma unroll
    for (int o = 0; o < 16; o++) pp[(size_t)o * 1024] = best[o];
  } else {
    float* gp = g_t + ((size_t)n * 1024 + m) * 128 + (og - 2) * 16;
    #pragma unroll
    for (int o4 = 0; o4 < 4; o4++) {
      float4 v = make_float4(best[o4 * 4], best[o4 * 4 + 1], best[o4 * 4 + 2], best[o4 * 4 + 3]);
      *(float4*)(gp + o4 * 4) = v;
    }
  }
}

// Fused attention: per block = (n, 16 queries): scores -> softmax -> P*g^T -> Wo + residual
__global__ __launch_bounds__(256) void attn_kernel(const float* __restrict__ x,
                                                   const float* __restrict__ ws,
                                                   const float* __restrict__ gamma_p,
                                                   float* __restrict__ out) {
  __shared__ float sc[16][1032];   // 66 KB, row stride 1032 (bank offset 8/row)
  __shared__ float th[16][32];     // 2 KB
  __shared__ float att[16][132];   // 8.25 KB, stride 132 (16B aligned rows)
  const float* theta = ws + WS_THETA;
  const float* phi   = ws + WS_PHI;
  const float* g_t   = ws + WS_GT;
  const float* Wo_s  = ws + 49152;
  int t = threadIdx.x;
  int n = blockIdx.y;
  int l0 = blockIdx.x * 16;

  for (int i = t; i < 512; i += 256) {
    int q = i >> 5, c = i & 31;
    th[q][c] = theta[((size_t)n * 32 + c) * 4096 + l0 + q];
  }
  __syncthreads();

  // Phase 1: scores[q][m] = theta_q . phi_m
  const float* php = phi + (size_t)n * 32 * 1024;
  #pragma unroll 1
  for (int k = 0; k < 4; k++) {
    int m = t + k * 256;
    float p[32];
    #pragma unroll
    for (int c = 0; c < 32; c++) p[c] = php[c * 1024 + m];
    #pragma unroll
    for (int q = 0; q < 16; q++) {
      const float4* thq = (const float4*)&th[q][0];
      float s = 0.f;
      #pragma unroll
      for (int c4 = 0; c4 < 8; c4++) {
        float4 w = thq[c4];
        s += w.x * p[c4 * 4] + w.y * p[c4 * 4 + 1] + w.z * p[c4 * 4 + 2] + w.w * p[c4 * 4 + 3];
      }
      sc[q][m] = s;
    }
  }
  __syncthreads();

  // Phase 2: softmax over m per row q. 16 lanes per row, elements strided by 16.
  {
    int q = t >> 4, lane = t & 15;
    float mx = -1e30f;
    for (int i = 0; i < 64; i++) mx = fmaxf(mx, sc[q][lane + i * 16]);
    #pragma unroll
    for (int off = 8; off > 0; off >>= 1) mx = fmaxf(mx, __shfl_xor(mx, off, 16));
    float sum = 0.f;
    for (int i = 0; i < 64; i++) {
      int m = lane + i * 16;
      float e = __expf(sc[q][m] - mx);
      sc[q][m] = e;
      sum += e;
    }
    #pragma unroll
    for (int off = 8; off > 0; off >>= 1) sum += __shfl_xor(sum, off, 16);
    float inv = 1.f / sum;
    for (int i = 0; i < 64; i++) sc[q][lane + i * 16] *= inv;
  }
  __syncthreads();

  // Phase 3: att[q][cg] = sum_m sc[q][m] * g_t[m][cg]
  {
    const float* gp = g_t + (size_t)n * 1024 * 128;
    int cg = t & 127;
    int qh = (t >> 7) * 8;
    float a[8];
    #pragma unroll
    for (int j = 0; j < 8; j++) a[j] = 0.f;
    for (int m = 0; m < 1024; m += 4) {
      float g0 = gp[(size_t)(m + 0) * 128 + cg];
      float g1 = gp[(size_t)(m + 1) * 128 + cg];
      float g2 = gp[(size_t)(m + 2) * 128 + cg];
      float g3 = gp[(size_t)(m + 3) * 128 + cg];
      #pragma unroll
      for (int j = 0; j < 8; j++) {
        float4 s4 = *(const float4*)&sc[qh + j][m];
        a[j] += s4.x * g0 + s4.y * g1 + s4.z * g2 + s4.w * g3;
      }
    }
    #pragma unroll
    for (int j = 0; j < 8; j++) att[qh + j][cg] = a[j];
  }
  __syncthreads();

  // Phase 4: out[n][oc][l] = x + gamma * (Wo_s[oc][:] . att[l][:])
  {
    int og = t >> 4, li = t & 15;
    float gm = gamma_p[0];
    const float* xp = x + ((size_t)n * 256) * 4096 + l0 + li;
    float* op = out + ((size_t)n * 256) * 4096 + l0 + li;
    const float4* arow = (const float4*)&att[li][0];
    #pragma unroll 1
    for (int j = 0; j < 16; j++) {
      int oc = og * 16 + j;
      const float4* wrow = (const float4*)(Wo_s + oc * 128);
      float acc = 0.f;
      #pragma unroll
      for (int c4 = 0; c4 < 32; c4++) {
        float4 w = wrow[c4];
        float4 av = arow[c4];
        acc += w.x * av.x + w.y * av.y + w.z * av.z + w.w * av.w;
      }
      op[(size_t)oc * 4096] = xp[(size_t)oc * 4096] + gm * acc;
    }
  }
}

extern "C" void kernel_launch(void* const* d_in, const int* in_sizes, int n_in,
                              void* d_out, int out_size, void* d_ws, size_t ws_size,
                              hipStream_t stream) {
  const float* x  = (const float*)d_in[0];
  const float* Wt = (const float*)d_in[1];
  const float* Wp = (const float*)d_in[2];
  const float* Wg = (const float*)d_in[3];
  const float* Wo = (const float*)d_in[4];
  const float* ut = (const float*)d_in[5];
  const float* up = (const float*)d_in[6];
  const float* ug = (const float*)d_in[7];
  const float* uo = (const float*)d_in[8];
  const float* gamma = (const float*)d_in[9];
  float* ws  = (float*)d_ws;
  float* out = (float*)d_out;

  sn_kernel<<<4, 256, 0, stream>>>(Wt, Wp, Wg, Wo, ut, up, ug, uo, ws);
  theta_kernel<<<dim3(16, 16), 256, 0, stream>>>(x, ws, ws + WS_THETA);
  pool_proj_kernel<<<dim3(4, 16, 10), 256, 0, stream>>>(x, ws, ws + WS_PHI, ws + WS_GT);
  attn_kernel<<<dim3(256, 16), 256, 0, stream>>>(x, ws, gamma, out);
}

// Round 2
// 556.401 us; speedup vs baseline: 3.0880x; 3.0880x over previous
//
#include <hip/hip_runtime.h>
#include <math.h>

#define EPS 1e-12f

typedef unsigned short ushort_t;
typedef __attribute__((ext_vector_type(8))) short short8;
typedef __attribute__((ext_vector_type(4))) float f32x4;

// ---- workspace layout (float units) ----
// 0       : Wt_s  (32*256)  fp32
// 8192    : Wp_s  (32*256)  fp32
// 16384   : Wg_s  (128*256) fp32
// 49152   : Wo_b  (256*128) bf16  (16384 floats worth)
// 65536   : theta_b [n][l][32c]  bf16 (16*4096*32 = 2M ushort = 1M floats)
// 1114112 : phi_b   [n][m][32c]  bf16 (16*1024*32 = 512K ushort)
// 1376256 : g_b     [n][cg][m]   bf16 (16*128*1024 = 2M ushort)
// total 2424832 floats = 9.7 MB
#define WS_WOB_F   49152
#define WS_THETA_F 65536
#define WS_PHI_F   1114112
#define WS_G_F     1376256

__device__ __forceinline__ ushort_t f2bf(float f) {
  unsigned int u = __float_as_uint(f);
  u += 0x7fffu + ((u >> 16) & 1u);
  return (ushort_t)(u >> 16);
}

__device__ __forceinline__ float block_reduce_sum(float v, float* red) {
  int t = threadIdx.x;
  red[t] = v;
  __syncthreads();
  #pragma unroll
  for (int s = 128; s > 0; s >>= 1) {
    if (t < s) red[t] += red[t + s];
    __syncthreads();
  }
  float r = red[0];
  __syncthreads();
  return r;
}

// One block per weight: spectral-norm scale W -> W/sigma into ws.
// Cases 0-2 write fp32 (consumed by fp32 projection kernels);
// case 3 (Wo) writes bf16 [oc][cg] (consumed by MFMA epilogue).
__global__ __launch_bounds__(256) void sn_kernel(
    const float* __restrict__ Wt, const float* __restrict__ Wp,
    const float* __restrict__ Wg, const float* __restrict__ Wo,
    const float* __restrict__ ut, const float* __restrict__ up,
    const float* __restrict__ ug, const float* __restrict__ uo,
    float* __restrict__ ws) {
  __shared__ float red[256];
  __shared__ float ub[256];
  __shared__ float vb[256];
  const float* W; const float* u; int O, Ci;
  switch (blockIdx.x) {
    case 0:  W = Wt; u = ut; O = 32;  Ci = 256; break;
    case 1:  W = Wp; u = up; O = 32;  Ci = 256; break;
    case 2:  W = Wg; u = ug; O = 128; Ci = 256; break;
    default: W = Wo; u = uo; O = 256; Ci = 128; break;
  }
  int t = threadIdx.x;
  if (t < O) ub[t] = u[t];
  __syncthreads();
  float tv = 0.f;
  if (t < Ci) {
    for (int o = 0; o < O; o++) tv += W[o * Ci + t] * ub[o];
  }
  float nt2 = block_reduce_sum((t < Ci) ? tv * tv : 0.f, red);
  float ntn = sqrtf(nt2);
  if (t < Ci) vb[t] = tv / (ntn + EPS);
  __syncthreads();
  float sv = 0.f;
  if (t < O) {
    for (int c = 0; c < Ci; c++) sv += W[t * Ci + c] * vb[c];
  }
  float ss = block_reduce_sum((t < O) ? sv * sv : 0.f, red);
  float ns = sqrtf(ss);
  float sigma = ss / (ns + EPS);
  float inv = 1.f / sigma;
  int total = O * Ci;
  if (blockIdx.x == 3) {
    ushort_t* wo = (ushort_t*)(ws + WS_WOB_F);
    for (int i = t; i < total; i += 256) wo[i] = f2bf(W[i] * inv);
  } else {
    float* Wout = (blockIdx.x == 0) ? ws : (blockIdx.x == 1) ? ws + 8192 : ws + 16384;
    for (int i = t; i < total; i += 256) Wout[i] = W[i] * inv;
  }
}

// theta_b[n][l][c] (bf16, c contiguous) = sum_c Wt_s[o][c] x[n][c][l]
__global__ __launch_bounds__(256) void theta_kernel(const float* __restrict__ x,
                                                    const float* __restrict__ Wsc,
                                                    ushort_t* __restrict__ theta_b) {
  __shared__ float4 Wl[32 * 64];   // [o][c4]  32 KB
  int t = threadIdx.x;
  const float4* W4 = (const float4*)Wsc;
  #pragma unroll
  for (int k = 0; k < 8; k++) Wl[t + k * 256] = W4[t + k * 256];
  __syncthreads();
  int n = blockIdx.y;
  int l = blockIdx.x * 256 + t;
  const float* xp = x + ((size_t)n * 256) * 4096 + l;
  float acc[32];
  #pragma unroll
  for (int o = 0; o < 32; o++) acc[o] = 0.f;
  for (int c4 = 0; c4 < 64; c4++) {
    float x0 = xp[(size_t)(c4 * 4 + 0) * 4096];
    float x1 = xp[(size_t)(c4 * 4 + 1) * 4096];
    float x2 = xp[(size_t)(c4 * 4 + 2) * 4096];
    float x3 = xp[(size_t)(c4 * 4 + 3) * 4096];
    #pragma unroll
    for (int o = 0; o < 32; o++) {
      float4 w = Wl[o * 64 + c4];
      acc[o] += w.x * x0 + w.y * x1 + w.z * x2 + w.w * x3;
    }
  }
  ushort_t* tp = theta_b + ((size_t)n * 4096 + l) * 32;
  #pragma unroll
  for (int k = 0; k < 4; k++) {
    short8 v;
    #pragma unroll
    for (int i = 0; i < 8; i++) v[i] = (short)f2bf(acc[k * 8 + i]);
    ((short8*)tp)[k] = v;
  }
}

// Pooled projections (fp32 math, bf16 outputs):
//   og 0..1 -> phi_b[n][m][32c] (c contiguous)
//   og 2..9 -> g_b[n][cg][m]    (m contiguous)
__global__ __launch_bounds__(256) void pool_proj_kernel(const float* __restrict__ x,
                                                        const float* __restrict__ ws,
                                                        ushort_t* __restrict__ phi_b,
                                                        ushort_t* __restrict__ g_b) {
  __shared__ float4 Wl[16 * 64];   // 16 KB
  int t = threadIdx.x;
  int og = blockIdx.z;  // 0..9
  const float* Wsrc = (og < 2) ? (ws + 8192 + og * 16 * 256)
                               : (ws + 16384 + (og - 2) * 16 * 256);
  const float4* W4 = (const float4*)Wsrc;
  #pragma unroll
  for (int k = 0; k < 4; k++) Wl[t + k * 256] = W4[t + k * 256];
  __syncthreads();
  int n = blockIdx.y;
  int m = blockIdx.x * 256 + t;
  int hd = m >> 5, wd = m & 31;
  int hw0 = hd * 128 + wd * 2;
  const float* xp = x + ((size_t)n * 256) * 4096;
  float best[16];
  #pragma unroll 1
  for (int sub = 0; sub < 4; sub++) {
    int off = hw0 + ((sub >> 1) * 64) + (sub & 1);
    float acc[16];
    #pragma unroll
    for (int o = 0; o < 16; o++) acc[o] = 0.f;
    for (int c4 = 0; c4 < 64; c4++) {
      float x0 = xp[(size_t)(c4 * 4 + 0) * 4096 + off];
      float x1 = xp[(size_t)(c4 * 4 + 1) * 4096 + off];
      float x2 = xp[(size_t)(c4 * 4 + 2) * 4096 + off];
      float x3 = xp[(size_t)(c4 * 4 + 3) * 4096 + off];
      #pragma unroll
      for (int o = 0; o < 16; o++) {
        float4 w = Wl[o * 64 + c4];
        acc[o] += w.x * x0 + w.y * x1 + w.z * x2 + w.w * x3;
      }
    }
    if (sub == 0) {
      #pragma unroll
      for (int o = 0; o < 16; o++) best[o] = acc[o];
    } else {
      #pragma unroll
      for (int o = 0; o < 16; o++) best[o] = fmaxf(best[o], acc[o]);
    }
  }
  if (og < 2) {
    ushort_t* pp = phi_b + ((size_t)n * 1024 + m) * 32 + og * 16;
    #pragma unroll
    for (int k = 0; k < 2; k++) {
      short8 v;
      #pragma unroll
      for (int i = 0; i < 8; i++) v[i] = (short)f2bf(best[k * 8 + i]);
      ((short8*)pp)[k] = v;
    }
  } else {
    ushort_t* gp = g_b + ((size_t)n * 128 + (og - 2) * 16) * 1024 + m;
    #pragma unroll
    for (int o = 0; o < 16; o++) gp[(size_t)o * 1024] = f2bf(best[o]);
  }
}

// Flash-style fused attention, bf16 MFMA. Block = (n, 16 queries), 4 waves.
// Wave w owns cg columns [w*32, w*32+32) for PV and oc [w*64, w*64+64) for epilogue.
__global__ __launch_bounds__(256) void attn_mfma(
    const float* __restrict__ x,
    const ushort_t* __restrict__ theta_b,
    const ushort_t* __restrict__ phi_b,
    const ushort_t* __restrict__ g_b,
    const ushort_t* __restrict__ Wo_b,
    const float* __restrict__ gamma_p,
    float* __restrict__ out) {
  __shared__ ushort_t Pb[16 * 136];   // P tile (16q x 128m) bf16, pitch 136; reused for O
  __shared__ float wmax[4][16];
  __shared__ float wsum[4][16];
  __shared__ float Mrow[16];
  __shared__ float Lrow[16];
  __shared__ float alphaA[16];
  __shared__ float outb[256][17];     // epilogue transpose, 17 KB

  const int t = threadIdx.x;
  const int w = t >> 6;
  const int lane = t & 63;
  const int quad = lane >> 4;
  const int l16 = lane & 15;
  const int n = blockIdx.y;
  const int l0 = blockIdx.x * 16;

  // theta A frag: A[q=l16][c=quad*8+j], one 16B load, held all kernel
  const short8 a_th = *(const short8*)(theta_b + ((size_t)n * 4096 + l0 + l16) * 32 + quad * 8);

  f32x4 oacc0 = {0.f, 0.f, 0.f, 0.f};
  f32x4 oacc1 = {0.f, 0.f, 0.f, 0.f};
  if (t < 16) { Mrow[t] = -3.0e38f; Lrow[t] = 0.f; }
  __syncthreads();

  const ushort_t* gp0 = g_b + ((size_t)n * 128 + w * 32 + l16) * 1024 + quad * 8;
  const ushort_t* gp1 = gp0 + 16 * 1024;
  const ushort_t* php = phi_b + ((size_t)n * 1024) * 32 + quad * 8;

  for (int mt = 0; mt < 8; ++mt) {
    const int m0 = mt * 128;
    // ---- scores: wave computes S[16q][32m] via 2 MFMAs ----
    short8 b0 = *(const short8*)(php + (size_t)(m0 + w * 32 + l16) * 32);
    short8 b1 = *(const short8*)(php + (size_t)(m0 + w * 32 + 16 + l16) * 32);
    f32x4 z = {0.f, 0.f, 0.f, 0.f};
    f32x4 s0 = __builtin_amdgcn_mfma_f32_16x16x32_bf16(a_th, b0, z, 0, 0, 0);
    f32x4 s1 = __builtin_amdgcn_mfma_f32_16x16x32_bf16(a_th, b1, z, 0, 0, 0);

    // ---- per-q max over wave's 32 m (reduce across 16 lanes per reg) ----
    float mx[4];
    #pragma unroll
    for (int r = 0; r < 4; ++r) {
      float m_ = fmaxf(s0[r], s1[r]);
      #pragma unroll
      for (int off = 8; off > 0; off >>= 1) m_ = fmaxf(m_, __shfl_xor(m_, off, 16));
      mx[r] = m_;
    }
    if (l16 == 0) {
      #pragma unroll
      for (int r = 0; r < 4; ++r) wmax[w][quad * 4 + r] = mx[r];
    }
    __syncthreads();
    if (t < 16) {
      float old = Mrow[t];
      float nm = fmaxf(old, fmaxf(fmaxf(wmax[0][t], wmax[1][t]), fmaxf(wmax[2][t], wmax[3][t])));
      float al = __expf(old - nm);
      Mrow[t] = nm; alphaA[t] = al; Lrow[t] *= al;
    }
    __syncthreads();
    // ---- exp, write P bf16, partial row sums, rescale O ----
    float ps[4];
    #pragma unroll
    for (int r = 0; r < 4; ++r) {
      int q = quad * 4 + r;
      float Mq = Mrow[q];
      float al = alphaA[q];
      float p0 = __expf(s0[r] - Mq);
      float p1 = __expf(s1[r] - Mq);
      Pb[q * 136 + w * 32 + l16] = f2bf(p0);
      Pb[q * 136 + w * 32 + 16 + l16] = f2bf(p1);
      ps[r] = p0 + p1;
      oacc0[r] *= al;
      oacc1[r] *= al;
    }
    #pragma unroll
    for (int r = 0; r < 4; ++r) {
      #pragma unroll
      for (int off = 8; off > 0; off >>= 1) ps[r] += __shfl_xor(ps[r], off, 16);
    }
    if (l16 == 0) {
      #pragma unroll
      for (int r = 0; r < 4; ++r) wsum[w][quad * 4 + r] = ps[r];
    }
    __syncthreads();
    if (t < 16) Lrow[t] += wsum[0][t] + wsum[1][t] + wsum[2][t] + wsum[3][t];
    // ---- PV: oacc[q][cg] += P[q][m] * g[m][cg], K=128 in 4 chunks ----
    #pragma unroll
    for (int kc = 0; kc < 4; ++kc) {
      short8 ap = *(const short8*)(Pb + l16 * 136 + kc * 32 + quad * 8);
      short8 g0 = *(const short8*)(gp0 + m0 + kc * 32);
      short8 g1 = *(const short8*)(gp1 + m0 + kc * 32);
      oacc0 = __builtin_amdgcn_mfma_f32_16x16x32_bf16(ap, g0, oacc0, 0, 0, 0);
      oacc1 = __builtin_amdgcn_mfma_f32_16x16x32_bf16(ap, g1, oacc1, 0, 0, 0);
    }
    // no end-of-loop barrier needed: next iteration's Pb writes are fenced by
    // two barriers (post-wmax, post-stats) that all waves must pass after PV.
  }
  __syncthreads();
  // ---- normalize O and stage bf16 into Pb (reuse) ----
  #pragma unroll
  for (int r = 0; r < 4; ++r) {
    int q = quad * 4 + r;
    float inv = 1.f / Lrow[q];
    Pb[q * 136 + w * 32 + l16] = f2bf(oacc0[r] * inv);
    Pb[q * 136 + w * 32 + 16 + l16] = f2bf(oacc1[r] * inv);
  }
  __syncthreads();
  // ---- output projection: D[q][oc] = sum_cg O[q][cg] * Wo[oc][cg] ----
  #pragma unroll
  for (int s2 = 0; s2 < 4; ++s2) {
    int oc0 = w * 64 + s2 * 16;
    f32x4 acc = {0.f, 0.f, 0.f, 0.f};
    #pragma unroll
    for (int kc = 0; kc < 4; ++kc) {
      short8 ao = *(const short8*)(Pb + l16 * 136 + kc * 32 + quad * 8);
      short8 bw = *(const short8*)(Wo_b + (size_t)(oc0 + l16) * 128 + kc * 32 + quad * 8);
      acc = __builtin_amdgcn_mfma_f32_16x16x32_bf16(ao, bw, acc, 0, 0, 0);
    }
    #pragma unroll
    for (int r = 0; r < 4; ++r) outb[oc0 + l16][quad * 4 + r] = acc[r];
  }
  __syncthreads();
  // ---- residual + coalesced 64B store per thread (thread t = oc) ----
  {
    float gm = gamma_p[0];
    const float* xr = x + ((size_t)n * 256 + t) * 4096 + l0;
    float* op = out + ((size_t)n * 256 + t) * 4096 + l0;
    #pragma unroll
    for (int i = 0; i < 4; ++i) {
      float4 xv = *(const float4*)(xr + i * 4);
      float4 v;
      v.x = xv.x + gm * outb[t][i * 4 + 0];
      v.y = xv.y + gm * outb[t][i * 4 + 1];
      v.z = xv.z + gm * outb[t][i * 4 + 2];
      v.w = xv.w + gm * outb[t][i * 4 + 3];
      *(float4*)(op + i * 4) = v;
    }
  }
}

extern "C" void kernel_launch(void* const* d_in, const int* in_sizes, int n_in,
                              void* d_out, int out_size, void* d_ws, size_t ws_size,
                              hipStream_t stream) {
  const float* x  = (const float*)d_in[0];
  const float* Wt = (const float*)d_in[1];
  const float* Wp = (const float*)d_in[2];
  const float* Wg = (const float*)d_in[3];
  const float* Wo = (const float*)d_in[4];
  const float* ut = (const float*)d_in[5];
  const float* up = (const float*)d_in[6];
  const float* ug = (const float*)d_in[7];
  const float* uo = (const float*)d_in[8];
  const float* gamma = (const float*)d_in[9];
  float* ws  = (float*)d_ws;
  float* out = (float*)d_out;

  ushort_t* Wo_b    = (ushort_t*)(ws + WS_WOB_F);
  ushort_t* theta_b = (ushort_t*)(ws + WS_THETA_F);
  ushort_t* phi_b   = (ushort_t*)(ws + WS_PHI_F);
  ushort_t* g_b     = (ushort_t*)(ws + WS_G_F);

  sn_kernel<<<4, 256, 0, stream>>>(Wt, Wp, Wg, Wo, ut, up, ug, uo, ws);
  theta_kernel<<<dim3(16, 16), 256, 0, stream>>>(x, ws, theta_b);
  pool_proj_kernel<<<dim3(4, 16, 10), 256, 0, stream>>>(x, ws, phi_b, g_b);
  attn_mfma<<<dim3(256, 16), 256, 0, stream>>>(x, theta_b, phi_b, g_b, Wo_b, gamma, out);
}

// Round 3
// 332.382 us; speedup vs baseline: 5.1693x; 1.6740x over previous
//
#include <hip/hip_runtime.h>
#include <math.h>

#define EPS 1e-12f

typedef unsigned short ushort_t;
typedef __attribute__((ext_vector_type(8))) short short8;
typedef __attribute__((ext_vector_type(4))) float f32x4;
typedef __attribute__((ext_vector_type(4))) unsigned short ushort4v;

// ---- workspace layout (float units) ----
// 0       : Wb   192x256 bf16 (theta rows 0..31, phi 32..63, g 64..191) = 24576 f
// 24576   : Wo_b 256x128 bf16 = 16384 f
// 40960   : theta_b [n][l][32c]  bf16 (16*4096*32)  = 1048576 f
// 1089536 : phi_b   [n][m][32c]  bf16 (16*1024*32)  = 262144 f
// 1351680 : g_b     [n][cg][m]   bf16 (16*128*1024) = 1048576 f
// total 2400256 floats = 9.6 MB
#define WS_WB_F 0
#define WS_WO_F 24576
#define WS_TH_F 40960
#define WS_PH_F 1089536
#define WS_G_F  1351680

__device__ __forceinline__ ushort_t f2bf(float f) {
  unsigned int u = __float_as_uint(f);
  u += 0x7fffu + ((u >> 16) & 1u);
  return (ushort_t)(u >> 16);
}
__device__ __forceinline__ float bf2f(ushort_t u) {
  return __uint_as_float(((unsigned int)u) << 16);
}

__device__ __forceinline__ float block_reduce_sum(float v, float* red) {
  int t = threadIdx.x;
  red[t] = v;
  __syncthreads();
  #pragma unroll
  for (int s = 128; s > 0; s >>= 1) {
    if (t < s) red[t] += red[t + s];
    __syncthreads();
  }
  float r = red[0];
  __syncthreads();
  return r;
}

// One block per weight: spectral-norm scale, emit bf16 weights.
// Cases 0..2 -> Wb rows {0,32,64}; case 3 -> Wo_b [oc][cg].
__global__ __launch_bounds__(256) void sn_kernel(
    const float* __restrict__ Wt, const float* __restrict__ Wp,
    const float* __restrict__ Wg, const float* __restrict__ Wo,
    const float* __restrict__ ut, const float* __restrict__ up,
    const float* __restrict__ ug, const float* __restrict__ uo,
    float* __restrict__ ws) {
  __shared__ float red[256];
  __shared__ float ub[256];
  __shared__ float vb[256];
  const float* W; const float* u; int O, Ci;
  switch (blockIdx.x) {
    case 0:  W = Wt; u = ut; O = 32;  Ci = 256; break;
    case 1:  W = Wp; u = up; O = 32;  Ci = 256; break;
    case 2:  W = Wg; u = ug; O = 128; Ci = 256; break;
    default: W = Wo; u = uo; O = 256; Ci = 128; break;
  }
  int t = threadIdx.x;
  if (t < O) ub[t] = u[t];
  __syncthreads();
  float tv = 0.f;
  if (t < Ci) {
    for (int o = 0; o < O; o++) tv += W[o * Ci + t] * ub[o];
  }
  float nt2 = block_reduce_sum((t < Ci) ? tv * tv : 0.f, red);
  float ntn = sqrtf(nt2);
  if (t < Ci) vb[t] = tv / (ntn + EPS);
  __syncthreads();
  float sv = 0.f;
  if (t < O) {
    for (int c = 0; c < Ci; c++) sv += W[t * Ci + c] * vb[c];
  }
  float ss = block_reduce_sum((t < O) ? sv * sv : 0.f, red);
  float ns = sqrtf(ss);
  float sigma = ss / (ns + EPS);
  float inv = 1.f / sigma;
  int total = O * Ci;
  ushort_t* dst;
  if (blockIdx.x == 3)      dst = (ushort_t*)(ws + WS_WO_F);
  else if (blockIdx.x == 0) dst = (ushort_t*)(ws + WS_WB_F);
  else if (blockIdx.x == 1) dst = (ushort_t*)(ws + WS_WB_F) + 32 * 256;
  else                      dst = (ushort_t*)(ws + WS_WB_F) + 64 * 256;
  for (int i = t; i < total; i += 256) dst[i] = f2bf(W[i] * inv);
}

// Fused projection GEMM: reads x once, LDS-transposes a 256c x 128px tile to
// bf16, MFMAs all 192 out-channels, fuses 2x2 maxpool for phi/g.
// Block = (l-tile of 128 px = 2 image rows, n). 4 waves; wave w owns px cols
// [w*16, w*16+16) of both rows (pooling pairs in-wave).
__global__ __launch_bounds__(256, 2) void proj_mfma(
    const float* __restrict__ x, const ushort_t* __restrict__ wb,
    ushort_t* __restrict__ theta_b, ushort_t* __restrict__ phi_b,
    ushort_t* __restrict__ g_b) {
  __shared__ ushort_t xb[128 * 264];   // [l][c], pitch 264 (16B-aligned rows, 2-way reads)
  const int t = threadIdx.x;
  const int n = blockIdx.y;
  const int l0 = blockIdx.x * 128;
  const float* xn = x + ((size_t)n * 256) * 4096 + l0;
  // ---- stage: x[c][l] fp32 -> xb[l][c] bf16 ----
  {
    const int lrel = t & 127;
    const int half = t >> 7;
    #pragma unroll 4
    for (int ch = 0; ch < 16; ++ch) {
      int chunk = half * 16 + ch;
      short8 v;
      #pragma unroll
      for (int j = 0; j < 8; ++j) {
        float f = xn[(size_t)(chunk * 8 + j) * 4096 + lrel];
        v[j] = (short)f2bf(f);
      }
      *(short8*)(&xb[lrel * 264 + chunk * 8]) = v;
    }
  }
  __syncthreads();
  const int w = t >> 6;
  const int lane = t & 63;
  const int quad = lane >> 4;
  const int l16 = lane & 15;
  const int rowA = (w * 16 + l16) * 264;
  const int rowB = (64 + w * 16 + l16) * 264;
  const int hd = blockIdx.x;  // pooled row index
  #pragma unroll 1
  for (int pass = 0; pass < 2; ++pass) {
    f32x4 accA[6], accB[6];
    #pragma unroll
    for (int i = 0; i < 6; ++i) {
      accA[i] = (f32x4){0.f, 0.f, 0.f, 0.f};
      accB[i] = (f32x4){0.f, 0.f, 0.f, 0.f};
    }
    #pragma unroll
    for (int kc = 0; kc < 8; ++kc) {
      short8 bA = *(const short8*)(&xb[rowA + kc * 32 + quad * 8]);
      short8 bB = *(const short8*)(&xb[rowB + kc * 32 + quad * 8]);
      #pragma unroll
      for (int mt = 0; mt < 6; ++mt) {
        int mtg = pass * 6 + mt;
        short8 aW = *(const short8*)(wb + (size_t)(mtg * 16 + l16) * 256 + kc * 32 + quad * 8);
        accA[mt] = __builtin_amdgcn_mfma_f32_16x16x32_bf16(aW, bA, accA[mt], 0, 0, 0);
        accB[mt] = __builtin_amdgcn_mfma_f32_16x16x32_bf16(aW, bB, accB[mt], 0, 0, 0);
      }
    }
    // ---- outputs: D[row=o_local=quad*4+r][col=px=l16] ----
    #pragma unroll
    for (int mt = 0; mt < 6; ++mt) {
      int mtg = pass * 6 + mt;
      if (mtg < 2) {
        int lA = l0 + w * 16 + l16;
        ushort4v vA, vB;
        #pragma unroll
        for (int r = 0; r < 4; ++r) { vA[r] = f2bf(accA[mt][r]); vB[r] = f2bf(accB[mt][r]); }
        *(ushort4v*)(theta_b + ((size_t)n * 4096 + lA) * 32 + mtg * 16 + quad * 4) = vA;
        *(ushort4v*)(theta_b + ((size_t)n * 4096 + lA + 64) * 32 + mtg * 16 + quad * 4) = vB;
      } else {
        float pm[4];
        #pragma unroll
        for (int r = 0; r < 4; ++r) {
          float v = fmaxf(accA[mt][r], accB[mt][r]);   // vertical pool (row pair)
          v = fmaxf(v, __shfl_xor(v, 1));              // horizontal pool (col pair)
          pm[r] = v;
        }
        if ((l16 & 1) == 0) {
          int m = hd * 32 + w * 8 + (l16 >> 1);
          if (mtg < 4) {
            ushort4v vv;
            #pragma unroll
            for (int r = 0; r < 4; ++r) vv[r] = f2bf(pm[r]);
            *(ushort4v*)(phi_b + ((size_t)n * 1024 + m) * 32 + (mtg - 2) * 16 + quad * 4) = vv;
          } else {
            int cg0 = (mtg - 4) * 16 + quad * 4;
            #pragma unroll
            for (int r = 0; r < 4; ++r)
              g_b[((size_t)n * 128 + cg0 + r) * 1024 + m] = f2bf(pm[r]);
          }
        }
      }
    }
  }
}

// Barrier-free flash attention: block = (64 queries, n), 4 waves.
// Each wave owns 16 queries end-to-end; P/O layout transforms via per-wave
// LDS (no __syncthreads in main loop). One barrier before the store epilogue.
__global__ __launch_bounds__(256, 3) void attn_mfma(
    const float* __restrict__ x,
    const ushort_t* __restrict__ theta_b,
    const ushort_t* __restrict__ phi_b,
    const ushort_t* __restrict__ g_b,
    const ushort_t* __restrict__ Wo_b,
    const float* __restrict__ gamma_p,
    float* __restrict__ out) {
  __shared__ ushort_t Pw[4][16 * 40];    // per-wave P / O-chunk staging (pitch 40)
  __shared__ ushort_t outb[256 * 68];    // [oc][l-rel] bf16, pitch 68; 34.8 KB

  const int t = threadIdx.x;
  const int w = t >> 6;
  const int lane = t & 63;
  const int quad = lane >> 4;
  const int l16 = lane & 15;
  const int n = blockIdx.y;
  const int l0 = blockIdx.x * 64;
  const int lq = l0 + w * 16;            // wave's query base
  ushort_t* PwW = Pw[w];

  // theta A-frag: A[q=l16][k=quad*8+j], held all kernel
  const short8 a_th = *(const short8*)(theta_b + ((size_t)n * 4096 + lq + l16) * 32 + quad * 8);
  const ushort_t* phiN = phi_b + (size_t)n * 1024 * 32;
  const ushort_t* gN   = g_b + (size_t)n * 128 * 1024;

  f32x4 oacc[8];
  #pragma unroll
  for (int j = 0; j < 8; ++j) oacc[j] = (f32x4){0.f, 0.f, 0.f, 0.f};
  float M[4], L[4];
  #pragma unroll
  for (int r = 0; r < 4; ++r) { M[r] = -3.0e38f; L[r] = 0.f; }

  #pragma unroll 1
  for (int mc = 0; mc < 32; ++mc) {
    const int m0 = mc * 32;
    // loads first (latency)
    short8 b0 = *(const short8*)(phiN + (size_t)(m0 + l16) * 32 + quad * 8);
    short8 b1 = *(const short8*)(phiN + (size_t)(m0 + 16 + l16) * 32 + quad * 8);
    short8 gf[8];
    #pragma unroll
    for (int j = 0; j < 8; ++j)
      gf[j] = *(const short8*)(gN + ((size_t)(j * 16 + l16)) * 1024 + m0 + quad * 8);
    f32x4 z = {0.f, 0.f, 0.f, 0.f};
    f32x4 s0 = __builtin_amdgcn_mfma_f32_16x16x32_bf16(a_th, b0, z, 0, 0, 0);
    f32x4 s1 = __builtin_amdgcn_mfma_f32_16x16x32_bf16(a_th, b1, z, 0, 0, 0);
    // online softmax, all intra-wave (16-lane reduces within quad rows)
    float alpha[4];
    #pragma unroll
    for (int r = 0; r < 4; ++r) {
      float mx = fmaxf(s0[r], s1[r]);
      #pragma unroll
      for (int off = 8; off > 0; off >>= 1) mx = fmaxf(mx, __shfl_xor(mx, off));
      float nm = fmaxf(M[r], mx);
      alpha[r] = __expf(M[r] - nm);
      M[r] = nm;
      float p0 = __expf(s0[r] - nm);
      float p1 = __expf(s1[r] - nm);
      int q = quad * 4 + r;
      PwW[q * 40 + l16] = f2bf(p0);
      PwW[q * 40 + 16 + l16] = f2bf(p1);
      float ps = p0 + p1;
      #pragma unroll
      for (int off = 8; off > 0; off >>= 1) ps += __shfl_xor(ps, off);
      L[r] = L[r] * alpha[r] + ps;
    }
    #pragma unroll
    for (int j = 0; j < 8; ++j) {
      #pragma unroll
      for (int r = 0; r < 4; ++r) oacc[j][r] *= alpha[r];
    }
    // P A-frag (C-layout -> A-layout via per-wave LDS), then PV
    short8 ap = *(const short8*)(PwW + l16 * 40 + quad * 8);
    #pragma unroll
    for (int j = 0; j < 8; ++j)
      oacc[j] = __builtin_amdgcn_mfma_f32_16x16x32_bf16(ap, gf[j], oacc[j], 0, 0, 0);
  }

  // ---- epilogue: D2[q][oc] = (O/L)[q][cg] . Wo[oc][cg], per 32-cg chunk ----
  float invL[4];
  #pragma unroll
  for (int r = 0; r < 4; ++r) invL[r] = 1.f / L[r];
  f32x4 acc2[16];
  #pragma unroll
  for (int i = 0; i < 16; ++i) acc2[i] = (f32x4){0.f, 0.f, 0.f, 0.f};
  #pragma unroll 1
  for (int kc = 0; kc < 4; ++kc) {
    #pragma unroll
    for (int r = 0; r < 4; ++r) {
      int q = quad * 4 + r;
      PwW[q * 40 + l16] = f2bf(oacc[2 * kc][r] * invL[r]);
      PwW[q * 40 + 16 + l16] = f2bf(oacc[2 * kc + 1][r] * invL[r]);
    }
    short8 aO = *(const short8*)(PwW + l16 * 40 + quad * 8);
    #pragma unroll
    for (int oct = 0; oct < 16; ++oct) {
      short8 bw = *(const short8*)(Wo_b + (size_t)(oct * 16 + l16) * 128 + kc * 32 + quad * 8);
      acc2[oct] = __builtin_amdgcn_mfma_f32_16x16x32_bf16(aO, bw, acc2[oct], 0, 0, 0);
    }
  }
  // stage D2 into outb[oc][l-rel]: lane holds (q=quad*4+r, oc=oct*16+l16)
  #pragma unroll
  for (int oct = 0; oct < 16; ++oct) {
    #pragma unroll
    for (int r = 0; r < 4; ++r)
      outb[(oct * 16 + l16) * 68 + w * 16 + quad * 4 + r] = f2bf(acc2[oct][r]);
  }
  __syncthreads();
  // ---- residual + coalesced stores ----
  {
    const float gm = gamma_p[0];
    const int oc = (t >> 4);        // 0..15 within group; row = ocg*16 + oc
    const int lch = (t & 15) * 4;
    #pragma unroll
    for (int ocg = 0; ocg < 16; ++ocg) {
      int row = ocg * 16 + oc;
      ushort4v ov = *(const ushort4v*)(&outb[row * 68 + lch]);
      const float* xp = x + ((size_t)n * 256 + row) * 4096 + l0 + lch;
      float* op = out + ((size_t)n * 256 + row) * 4096 + l0 + lch;
      float4 xv = *(const float4*)xp;
      float4 v;
      v.x = xv.x + gm * bf2f(ov[0]);
      v.y = xv.y + gm * bf2f(ov[1]);
      v.z = xv.z + gm * bf2f(ov[2]);
      v.w = xv.w + gm * bf2f(ov[3]);
      *(float4*)op = v;
    }
  }
}

extern "C" void kernel_launch(void* const* d_in, const int* in_sizes, int n_in,
                              void* d_out, int out_size, void* d_ws, size_t ws_size,
                              hipStream_t stream) {
  const float* x  = (const float*)d_in[0];
  const float* Wt = (const float*)d_in[1];
  const float* Wp = (const float*)d_in[2];
  const float* Wg = (const float*)d_in[3];
  const float* Wo = (const float*)d_in[4];
  const float* ut = (const float*)d_in[5];
  const float* up = (const float*)d_in[6];
  const float* ug = (const float*)d_in[7];
  const float* uo = (const float*)d_in[8];
  const float* gamma = (const float*)d_in[9];
  float* ws  = (float*)d_ws;
  float* out = (float*)d_out;

  ushort_t* wb      = (ushort_t*)(ws + WS_WB_F);
  ushort_t* Wo_b    = (ushort_t*)(ws + WS_WO_F);
  ushort_t* theta_b = (ushort_t*)(ws + WS_TH_F);
  ushort_t* phi_b   = (ushort_t*)(ws + WS_PH_F);
  ushort_t* g_b     = (ushort_t*)(ws + WS_G_F);

  sn_kernel<<<4, 256, 0, stream>>>(Wt, Wp, Wg, Wo, ut, up, ug, uo, ws);
  proj_mfma<<<dim3(32, 16), 256, 0, stream>>>(x, wb, theta_b, phi_b, g_b);
  attn_mfma<<<dim3(64, 16), 256, 0, stream>>>(x, theta_b, phi_b, g_b, Wo_b, gamma, out);
}